// Round 1
// baseline (163.889 us; speedup 1.0000x reference)
//
#include <hip/hip_runtime.h>
#include <math.h>

#define A_   16
#define N_   1000
#define F_   16
#define E_   16000
#define D_   128
#define CAP_ 64

__device__ __forceinline__ float lrelu(float v){ return v > 0.0f ? v : 0.2f*v; }

// ---------------- k_init: map=-1, find agent node per graph ----------------
__global__ void k_init(const float* __restrict__ nf, int* __restrict__ agent_node,
                       int* __restrict__ map){
  int i = blockIdx.x*blockDim.x + threadIdx.x;
  if (i >= A_*N_) return;
  map[i] = -1;
  if (nf[i*F_] == 1.0f) agent_node[i / N_] = i % N_;
}

// ---------------- k_build_list1: agent + in-neighbors (shared topology) ----
__global__ void k_build_list1(const int* __restrict__ ei, const int* __restrict__ agent_node,
                              int* __restrict__ list1, int* __restrict__ count1,
                              int* __restrict__ map){
  int a = blockIdx.x;
  int lane = threadIdx.x;            // block = 64 = one wave
  int d = agent_node[a];
  if (lane == 0){ list1[a*CAP_] = d; map[a*N_ + d] = 0; }
  int cnt = 1;
  for (int base = 0; base < E_; base += 64){
    int dst = ei[E_ + base + lane];
    int src = ei[base + lane];
    unsigned long long mask = __ballot(dst == d);
    if (dst == d){
      int pos = cnt + (int)__popcll(mask & ((1ull << lane) - 1ull));
      if (pos < CAP_){ list1[a*CAP_ + pos] = src; map[a*N_ + src] = pos; }
    }
    cnt += (int)__popcll(mask);
  }
  if (lane == 0) count1[a] = (cnt < CAP_) ? cnt : CAP_;
}

// ---------------- k_attn1: GATv2 layer 1 (4 heads x 32) + LN + ReLU --------
// one wave per (graph, list1 slot); xl1/xr1 computed on the fly (K=16 GEMV)
__global__ void __launch_bounds__(256) k_attn1(
    const float* __restrict__ nf, const int* __restrict__ ei,
    const int* __restrict__ list1, const int* __restrict__ count1,
    const float* __restrict__ Wl1, const float* __restrict__ Wr1,
    const float* __restrict__ att1, const float* __restrict__ b1,
    const float* __restrict__ lnw, const float* __restrict__ lnb,
    float* __restrict__ h_c){
  int wid  = blockIdx.x*(blockDim.x >> 6) + (threadIdx.x >> 6);
  int lane = threadIdx.x & 63;
  int a = wid >> 6;                   // CAP_ == 64
  int i = wid & (CAP_ - 1);
  if (a >= A_) return;
  if (i >= count1[a]) return;
  int d  = list1[a*CAP_ + i];
  int c0 = lane*2;

  // xr (dst side), and keep per-lane Wl slice in registers
  float wl0[F_], wl1v[F_];
  float xr0 = 0.f, xr1 = 0.f;
  {
    const float* xd = &nf[(a*N_ + d)*F_];
    #pragma unroll
    for (int k = 0; k < F_; ++k){
      float2 wr = *(const float2*)&Wr1[k*D_ + c0];
      float xv = xd[k];
      xr0 += xv*wr.x; xr1 += xv*wr.y;
    }
  }
  #pragma unroll
  for (int k = 0; k < F_; ++k){
    float2 wl = *(const float2*)&Wl1[k*D_ + c0];
    wl0[k] = wl.x; wl1v[k] = wl.y;
  }
  int head = lane >> 4;
  float at0 = att1[head*32 + (c0 & 31)];
  float at1 = att1[head*32 + ((c0+1) & 31)];

  float m = -INFINITY, lsum = 0.f, acc0 = 0.f, acc1 = 0.f;
  auto process = [&](int s){
    const float* xs = &nf[(a*N_ + s)*F_];
    float xl0 = 0.f, xl1 = 0.f;
    #pragma unroll
    for (int k = 0; k < F_; ++k){
      float xv = xs[k];
      xl0 += xv*wl0[k]; xl1 += xv*wl1v[k];
    }
    float t = lrelu(xl0 + xr0)*at0 + lrelu(xl1 + xr1)*at1;
    t += __shfl_xor(t,1); t += __shfl_xor(t,2);
    t += __shfl_xor(t,4); t += __shfl_xor(t,8);   // 16-lane head groups
    float mn = fmaxf(m, t);
    float sc = expf(m - mn);
    float p  = expf(t - mn);
    lsum = lsum*sc + p;
    acc0 = acc0*sc + p*xl0;
    acc1 = acc1*sc + p*xl1;
    m = mn;
  };

  process(d);                          // the appended self-loop
  for (int base = 0; base < E_; base += 64){
    int dst  = ei[E_ + base + lane];
    int srcv = ei[base + lane];
    unsigned long long mask = __ballot(dst == d);
    while (mask){
      int p = __builtin_ctzll(mask); mask &= mask - 1;
      int s = __shfl(srcv, p);
      process(s);
    }
  }

  float inv = 1.0f/lsum;
  float v0 = acc0*inv + b1[c0];
  float v1 = acc1*inv + b1[c0+1];
  // fused LayerNorm over 128 (whole wave) + ReLU
  float ss = v0 + v1;
  ss += __shfl_xor(ss,1);  ss += __shfl_xor(ss,2);  ss += __shfl_xor(ss,4);
  ss += __shfl_xor(ss,8);  ss += __shfl_xor(ss,16); ss += __shfl_xor(ss,32);
  float mu = ss*(1.0f/D_);
  float d0 = v0 - mu, d1 = v1 - mu;
  float vs = d0*d0 + d1*d1;
  vs += __shfl_xor(vs,1);  vs += __shfl_xor(vs,2);  vs += __shfl_xor(vs,4);
  vs += __shfl_xor(vs,8);  vs += __shfl_xor(vs,16); vs += __shfl_xor(vs,32);
  float rinv = rsqrtf(vs*(1.0f/D_) + 1e-5f);
  float h0 = fmaxf(d0*rinv*lnw[c0]   + lnb[c0],   0.0f);
  float h1 = fmaxf(d1*rinv*lnw[c0+1] + lnb[c0+1], 0.0f);
  *(float2*)&h_c[(a*CAP_ + i)*D_ + c0] = make_float2(h0, h1);
}

// ---------------- k_gemm2: xl2 for list1 slots, xr2 for agents -------------
__global__ void __launch_bounds__(256) k_gemm2(
    const float* __restrict__ h_c, const int* __restrict__ count1,
    const float* __restrict__ Wl2, const float* __restrict__ Wr2,
    float* __restrict__ xl2_c, float* __restrict__ xr2){
  int wid  = blockIdx.x*(blockDim.x >> 6) + (threadIdx.x >> 6);
  int lane = threadIdx.x & 63;
  int a = wid / (CAP_ + 1);
  int i = wid - a*(CAP_ + 1);
  if (a >= A_) return;
  const float* W; const float* hrow; float* out;
  if (i == CAP_){                      // xr2 of agent (h slot 0)
    W = Wr2; hrow = &h_c[(a*CAP_)*D_]; out = &xr2[a*D_];
  } else {
    if (i >= count1[a]) return;
    W = Wl2; hrow = &h_c[(a*CAP_ + i)*D_]; out = &xl2_c[(a*CAP_ + i)*D_];
  }
  int c0 = lane*2;
  float acc0 = 0.f, acc1 = 0.f;
  #pragma unroll 8
  for (int k = 0; k < D_; ++k){
    float hk = hrow[k];
    float2 w = *(const float2*)&W[k*D_ + c0];
    acc0 += hk*w.x; acc1 += hk*w.y;
  }
  *(float2*)&out[c0] = make_float2(acc0, acc1);
}

// ---------------- k_attn2: GATv2 layer 2 (1 head x 128) at agent nodes -----
__global__ void __launch_bounds__(256) k_attn2(
    const float* __restrict__ xl2_c, const float* __restrict__ xr2,
    const int* __restrict__ ei, const int* __restrict__ agent_node,
    const int* __restrict__ map, const float* __restrict__ att2,
    const float* __restrict__ b2, float* __restrict__ af){
  int wid  = blockIdx.x*(blockDim.x >> 6) + (threadIdx.x >> 6);
  int lane = threadIdx.x & 63;
  if (wid >= A_) return;
  int a = wid;
  int d = agent_node[a];
  int c0 = lane*2;
  float2 xr = *(const float2*)&xr2[a*D_ + c0];
  float at0 = att2[c0], at1 = att2[c0+1];
  float m = -INFINITY, lsum = 0.f, acc0 = 0.f, acc1 = 0.f;
  auto process = [&](int s){
    int slot = map[a*N_ + s];
    float2 xl = *(const float2*)&xl2_c[(a*CAP_ + slot)*D_ + c0];
    float t = lrelu(xl.x + xr.x)*at0 + lrelu(xl.y + xr.y)*at1;
    t += __shfl_xor(t,1);  t += __shfl_xor(t,2);  t += __shfl_xor(t,4);
    t += __shfl_xor(t,8);  t += __shfl_xor(t,16); t += __shfl_xor(t,32);
    float mn = fmaxf(m, t);
    float sc = expf(m - mn);
    float p  = expf(t - mn);
    lsum = lsum*sc + p;
    acc0 = acc0*sc + p*xl.x;
    acc1 = acc1*sc + p*xl.y;
    m = mn;
  };
  process(d);                          // self-loop
  for (int base = 0; base < E_; base += 64){
    int dst  = ei[E_ + base + lane];
    int srcv = ei[base + lane];
    unsigned long long mask = __ballot(dst == d);
    while (mask){
      int p = __builtin_ctzll(mask); mask &= mask - 1;
      process(__shfl(srcv, p));
    }
  }
  float inv = 1.0f/lsum;
  af[a*D_ + c0]     = acc0*inv + b2[c0];
  af[a*D_ + c0 + 1] = acc1*inv + b2[c0+1];
}

// ---------------- k_gru: GRU cell + actor/critic heads ---------------------
__global__ void k_gru(const float* __restrict__ af, const float* __restrict__ hs,
                      const float* __restrict__ Wih, const float* __restrict__ Whh,
                      const float* __restrict__ bih, const float* __restrict__ bhh,
                      const float* __restrict__ Wa, const float* __restrict__ ba,
                      const float* __restrict__ Wv, const float* __restrict__ bv,
                      const int* __restrict__ amask, float* __restrict__ out){
  int a = blockIdx.x;
  int j = threadIdx.x;                 // 128 threads
  __shared__ float fx[D_], fh[D_], nh[D_];
  fx[j] = af[a*D_ + j];
  fh[j] = hs[a*D_ + j];
  __syncthreads();
  float gi_r = bih[j], gi_z = bih[D_ + j], gi_n = bih[2*D_ + j];
  float gh_r = bhh[j], gh_z = bhh[D_ + j], gh_n = bhh[2*D_ + j];
  #pragma unroll 4
  for (int k = 0; k < D_; ++k){
    float xv = fx[k], hv = fh[k];
    gi_r += xv*Wih[(j      )*D_ + k];
    gi_z += xv*Wih[(D_  + j)*D_ + k];
    gi_n += xv*Wih[(2*D_+ j)*D_ + k];
    gh_r += hv*Whh[(j      )*D_ + k];
    gh_z += hv*Whh[(D_  + j)*D_ + k];
    gh_n += hv*Whh[(2*D_+ j)*D_ + k];
  }
  float r = 1.0f/(1.0f + expf(-(gi_r + gh_r)));
  float z = 1.0f/(1.0f + expf(-(gi_z + gh_z)));
  float n = tanhf(gi_n + r*gh_n);
  float nhv = (1.0f - z)*n + z*fh[j];
  nh[j] = nhv;
  out[256 + 16 + a*D_ + j] = nhv;      // next_h
  __syncthreads();
  if (j < 16){
    float lg = ba[j];
    #pragma unroll 8
    for (int k = 0; k < D_; ++k) lg += nh[k]*Wa[k*16 + j];
    if (amask[a*16 + j] == 0) lg = -1e8f;
    out[a*16 + j] = lg;                // logits
  }
  if (j == 16){
    float v = bv[0];
    #pragma unroll 8
    for (int k = 0; k < D_; ++k) v += nh[k]*Wv[k];
    out[256 + a] = v;                  // values
  }
}

// ---------------------------------------------------------------------------
extern "C" void kernel_launch(void* const* d_in, const int* in_sizes, int n_in,
                              void* d_out, int out_size, void* d_ws, size_t ws_size,
                              hipStream_t stream){
  const float* nf   = (const float*)d_in[0];
  const int*   ei   = (const int*)  d_in[1];
  const float* hs   = (const float*)d_in[2];
  const int*   am   = (const int*)  d_in[3];
  const float* Wl1  = (const float*)d_in[4];
  const float* Wr1  = (const float*)d_in[5];
  const float* att1 = (const float*)d_in[6];
  const float* b1   = (const float*)d_in[7];
  const float* lnw  = (const float*)d_in[8];
  const float* lnb  = (const float*)d_in[9];
  const float* Wl2  = (const float*)d_in[10];
  const float* Wr2  = (const float*)d_in[11];
  const float* att2 = (const float*)d_in[12];
  const float* b2   = (const float*)d_in[13];
  const float* Wih  = (const float*)d_in[14];
  const float* Whh  = (const float*)d_in[15];
  const float* bih  = (const float*)d_in[16];
  const float* bhh  = (const float*)d_in[17];
  const float* Wa   = (const float*)d_in[18];
  const float* ba   = (const float*)d_in[19];
  const float* Wv   = (const float*)d_in[20];
  const float* bv   = (const float*)d_in[21];
  float* out = (float*)d_out;

  char* ws = (char*)d_ws;
  float* h_c        = (float*)(ws);                 // 16*64*128 f32 = 512 KiB
  float* xl2_c      = (float*)(ws + 524288);        // 512 KiB
  float* xr2        = (float*)(ws + 1048576);       // 8 KiB
  float* af         = (float*)(ws + 1056768);       // 8 KiB
  int*   agent_node = (int*)  (ws + 1064960);       // 64 B
  int*   list1      = (int*)  (ws + 1065024);       // 4 KiB
  int*   count1     = (int*)  (ws + 1069120);       // 64 B
  int*   map        = (int*)  (ws + 1069184);       // 62.5 KiB

  k_init       <<<(A_*N_ + 255)/256, 256, 0, stream>>>(nf, agent_node, map);
  k_build_list1<<<A_, 64, 0, stream>>>(ei, agent_node, list1, count1, map);
  k_attn1      <<<(A_*CAP_)/4, 256, 0, stream>>>(nf, ei, list1, count1,
                                                 Wl1, Wr1, att1, b1, lnw, lnb, h_c);
  k_gemm2      <<<(A_*(CAP_+1) + 3)/4, 256, 0, stream>>>(h_c, count1, Wl2, Wr2, xl2_c, xr2);
  k_attn2      <<<(A_ + 3)/4, 256, 0, stream>>>(xl2_c, xr2, ei, agent_node, map, att2, b2, af);
  k_gru        <<<A_, D_, 0, stream>>>(af, hs, Wih, Whh, bih, bhh, Wa, ba, Wv, bv, am, out);
}

// Round 2
// 64.706 us; speedup vs baseline: 2.5328x; 2.5328x over previous
//
#include <hip/hip_runtime.h>
#include <math.h>

#define A_    16
#define N_    1000
#define F_    16
#define E_    16000
#define D_    128
#define CAP2_ 64          // max in-degree tracked per node (Poisson(16) -> safe)
#define SLOTS_ 65         // per-agent compact rows: slot0 = agent node, 1..64 = edges

__device__ __forceinline__ float lrelu(float v){ return v > 0.0f ? v : 0.2f*v; }

// ---------------- k_init: clear counters, find agent node per graph --------
__global__ void k_init(const float* __restrict__ nf, int* __restrict__ agent_node,
                       int* __restrict__ ncount){
  int i = blockIdx.x*blockDim.x + threadIdx.x;
  if (i < N_) ncount[i] = 0;
  if (i < A_*N_ && nf[i*F_] == 1.0f) agent_node[i / N_] = i % N_;
}

// ---------------- k_scan: one parallel pass -> inverted adjacency ----------
__global__ void k_scan(const int* __restrict__ ei, int* __restrict__ ncount,
                       int* __restrict__ nbrs){
  int e = blockIdx.x*blockDim.x + threadIdx.x;
  if (e >= E_) return;
  int src = ei[e];
  int dst = ei[E_ + e];
  int pos = atomicAdd(&ncount[dst], 1);
  if (pos < CAP2_) nbrs[dst*CAP2_ + pos] = src;
}

// ---------------- k_attn1: GATv2 layer 1 (4 heads x 32) + LN + ReLU --------
// one wave per (agent, slot); neighbor features staged to LDS in parallel
__global__ void __launch_bounds__(256) k_attn1(
    const float* __restrict__ nf, const int* __restrict__ agent_node,
    const int* __restrict__ ncount, const int* __restrict__ nbrs,
    const float* __restrict__ Wl1, const float* __restrict__ Wr1,
    const float* __restrict__ att1, const float* __restrict__ b1,
    const float* __restrict__ lnw, const float* __restrict__ lnb,
    float* __restrict__ h_c){
  int wid  = blockIdx.x*(blockDim.x >> 6) + (threadIdx.x >> 6);
  int lane = threadIdx.x & 63;
  int w    = (threadIdx.x >> 6) & 3;
  int a = wid / SLOTS_;
  int i = wid - a*SLOTS_;
  if (a >= A_) return;
  int d_a = agent_node[a];
  int c = min(ncount[d_a], CAP2_);
  if (i > c) return;
  int v = (i == 0) ? d_a : nbrs[d_a*CAP2_ + (i-1)];
  int cnt = min(ncount[v], CAP2_);

  __shared__ float feat[4][(CAP2_ + 1)*F_];
  float* fb = feat[w];

  // per-lane neighbor id
  int nid = (lane < cnt) ? nbrs[v*CAP2_ + lane] : 0;
  // stage self features (slot 0) — float4 by lanes 0..3
  if (lane < 4)
    *(float4*)&fb[lane*4] = *(const float4*)&nf[(a*N_ + v)*F_ + lane*4];
  // stage neighbor features in one parallel round
  for (int t = lane; t < cnt*4; t += 64){
    int j  = t >> 2;
    int k4 = (t & 3)*4;
    int s  = __shfl(nid, j);
    *(float4*)&fb[F_ + j*F_ + k4] = *(const float4*)&nf[(a*N_ + s)*F_ + k4];
  }
  asm volatile("s_waitcnt lgkmcnt(0)" ::: "memory");

  int c0 = lane*2;
  // per-lane Wl slice in registers; xr from self feats
  float wl0[F_], wl1v[F_];
  #pragma unroll
  for (int k = 0; k < F_; ++k){
    float2 wl = *(const float2*)&Wl1[k*D_ + c0];
    wl0[k] = wl.x; wl1v[k] = wl.y;
  }
  float xr0 = 0.f, xr1 = 0.f;
  #pragma unroll
  for (int k = 0; k < F_; ++k){
    float2 wr = *(const float2*)&Wr1[k*D_ + c0];
    float xv = fb[k];
    xr0 += xv*wr.x; xr1 += xv*wr.y;
  }
  int head = lane >> 4;
  float at0 = att1[head*32 + (c0 & 31)];
  float at1 = att1[head*32 + ((c0+1) & 31)];

  float m = -INFINITY, lsum = 0.f, acc0 = 0.f, acc1 = 0.f;
  auto process = [&](int off){
    float xl0 = 0.f, xl1 = 0.f;
    #pragma unroll
    for (int k = 0; k < F_; k += 4){
      float4 xv = *(const float4*)&fb[off + k];
      xl0 += xv.x*wl0[k] + xv.y*wl0[k+1] + xv.z*wl0[k+2] + xv.w*wl0[k+3];
      xl1 += xv.x*wl1v[k] + xv.y*wl1v[k+1] + xv.z*wl1v[k+2] + xv.w*wl1v[k+3];
    }
    float t = lrelu(xl0 + xr0)*at0 + lrelu(xl1 + xr1)*at1;
    t += __shfl_xor(t,1); t += __shfl_xor(t,2);
    t += __shfl_xor(t,4); t += __shfl_xor(t,8);   // 16-lane head groups
    float mn = fmaxf(m, t);
    float sc = expf(m - mn);
    float p  = expf(t - mn);
    lsum = lsum*sc + p;
    acc0 = acc0*sc + p*xl0;
    acc1 = acc1*sc + p*xl1;
    m = mn;
  };

  process(0);                           // self-loop
  for (int j = 0; j < cnt; ++j) process(F_ + j*F_);

  float inv = 1.0f/lsum;
  float v0 = acc0*inv + b1[c0];
  float v1 = acc1*inv + b1[c0+1];
  // fused LayerNorm over 128 (whole wave) + ReLU
  float ss = v0 + v1;
  ss += __shfl_xor(ss,1);  ss += __shfl_xor(ss,2);  ss += __shfl_xor(ss,4);
  ss += __shfl_xor(ss,8);  ss += __shfl_xor(ss,16); ss += __shfl_xor(ss,32);
  float mu = ss*(1.0f/D_);
  float d0 = v0 - mu, d1 = v1 - mu;
  float vs = d0*d0 + d1*d1;
  vs += __shfl_xor(vs,1);  vs += __shfl_xor(vs,2);  vs += __shfl_xor(vs,4);
  vs += __shfl_xor(vs,8);  vs += __shfl_xor(vs,16); vs += __shfl_xor(vs,32);
  float rinv = rsqrtf(vs*(1.0f/D_) + 1e-5f);
  float h0 = fmaxf(d0*rinv*lnw[c0]   + lnb[c0],   0.0f);
  float h1 = fmaxf(d1*rinv*lnw[c0+1] + lnb[c0+1], 0.0f);
  *(float2*)&h_c[(a*SLOTS_ + i)*D_ + c0] = make_float2(h0, h1);
}

// ---------------- k_gemm2: xl2 for slots, xr2 for agents -------------------
__global__ void __launch_bounds__(256) k_gemm2(
    const float* __restrict__ h_c, const int* __restrict__ agent_node,
    const int* __restrict__ ncount,
    const float* __restrict__ Wl2, const float* __restrict__ Wr2,
    float* __restrict__ xl2_c, float* __restrict__ xr2){
  int wid  = blockIdx.x*(blockDim.x >> 6) + (threadIdx.x >> 6);
  int lane = threadIdx.x & 63;
  int a = wid / (SLOTS_ + 1);
  int i = wid - a*(SLOTS_ + 1);
  if (a >= A_) return;
  int c = min(ncount[agent_node[a]], CAP2_);
  const float* W; const float* hrow; float* out;
  if (i == SLOTS_){                    // xr2 of agent (h slot 0)
    W = Wr2; hrow = &h_c[(a*SLOTS_)*D_]; out = &xr2[a*D_];
  } else {
    if (i > c) return;
    W = Wl2; hrow = &h_c[(a*SLOTS_ + i)*D_]; out = &xl2_c[(a*SLOTS_ + i)*D_];
  }
  int c0 = lane*2;
  float acc0 = 0.f, acc1 = 0.f;
  #pragma unroll 8
  for (int k = 0; k < D_; ++k){
    float hk = hrow[k];
    float2 ww = *(const float2*)&W[k*D_ + c0];
    acc0 += hk*ww.x; acc1 += hk*ww.y;
  }
  *(float2*)&out[c0] = make_float2(acc0, acc1);
}

// ---------------- k_attn2: GATv2 layer 2 (1 head x 128) at agent nodes -----
__global__ void __launch_bounds__(256) k_attn2(
    const float* __restrict__ xl2_c, const float* __restrict__ xr2,
    const int* __restrict__ agent_node, const int* __restrict__ ncount,
    const float* __restrict__ att2, const float* __restrict__ b2,
    float* __restrict__ af){
  int wid  = blockIdx.x*(blockDim.x >> 6) + (threadIdx.x >> 6);
  int lane = threadIdx.x & 63;
  if (wid >= A_) return;
  int a = wid;
  int c = min(ncount[agent_node[a]], CAP2_);
  int c0 = lane*2;
  float2 xr = *(const float2*)&xr2[a*D_ + c0];
  float at0 = att2[c0], at1 = att2[c0+1];
  float m = -INFINITY, lsum = 0.f, acc0 = 0.f, acc1 = 0.f;

  float2 xl = *(const float2*)&xl2_c[(a*SLOTS_)*D_ + c0];   // slot 0 = self
  for (int i = 0; i <= c; ++i){
    float2 cur = xl;
    if (i < c) xl = *(const float2*)&xl2_c[(a*SLOTS_ + i + 1)*D_ + c0];  // prefetch
    float t = lrelu(cur.x + xr.x)*at0 + lrelu(cur.y + xr.y)*at1;
    t += __shfl_xor(t,1);  t += __shfl_xor(t,2);  t += __shfl_xor(t,4);
    t += __shfl_xor(t,8);  t += __shfl_xor(t,16); t += __shfl_xor(t,32);
    float mn = fmaxf(m, t);
    float sc = expf(m - mn);
    float p  = expf(t - mn);
    lsum = lsum*sc + p;
    acc0 = acc0*sc + p*cur.x;
    acc1 = acc1*sc + p*cur.y;
    m = mn;
  }
  float inv = 1.0f/lsum;
  af[a*D_ + c0]     = acc0*inv + b2[c0];
  af[a*D_ + c0 + 1] = acc1*inv + b2[c0+1];
}

// ---------------- k_gru: GRU cell + actor/critic heads ---------------------
__global__ void k_gru(const float* __restrict__ af, const float* __restrict__ hs,
                      const float* __restrict__ Wih, const float* __restrict__ Whh,
                      const float* __restrict__ bih, const float* __restrict__ bhh,
                      const float* __restrict__ Wa, const float* __restrict__ ba,
                      const float* __restrict__ Wv, const float* __restrict__ bv,
                      const int* __restrict__ amask, float* __restrict__ out){
  int a = blockIdx.x;
  int j = threadIdx.x;                 // 128 threads
  __shared__ float fx[D_], fh[D_], nh[D_];
  fx[j] = af[a*D_ + j];
  fh[j] = hs[a*D_ + j];
  __syncthreads();
  float gi_r = bih[j], gi_z = bih[D_ + j], gi_n = bih[2*D_ + j];
  float gh_r = bhh[j], gh_z = bhh[D_ + j], gh_n = bhh[2*D_ + j];
  #pragma unroll 4
  for (int k = 0; k < D_; ++k){
    float xv = fx[k], hv = fh[k];
    gi_r += xv*Wih[(j      )*D_ + k];
    gi_z += xv*Wih[(D_  + j)*D_ + k];
    gi_n += xv*Wih[(2*D_+ j)*D_ + k];
    gh_r += hv*Whh[(j      )*D_ + k];
    gh_z += hv*Whh[(D_  + j)*D_ + k];
    gh_n += hv*Whh[(2*D_+ j)*D_ + k];
  }
  float r = 1.0f/(1.0f + expf(-(gi_r + gh_r)));
  float z = 1.0f/(1.0f + expf(-(gi_z + gh_z)));
  float n = tanhf(gi_n + r*gh_n);
  float nhv = (1.0f - z)*n + z*fh[j];
  nh[j] = nhv;
  out[256 + 16 + a*D_ + j] = nhv;      // next_h
  __syncthreads();
  if (j < 16){
    float lg = ba[j];
    #pragma unroll 8
    for (int k = 0; k < D_; ++k) lg += nh[k]*Wa[k*16 + j];
    if (amask[a*16 + j] == 0) lg = -1e8f;
    out[a*16 + j] = lg;                // logits
  }
  if (j == 16){
    float v = bv[0];
    #pragma unroll 8
    for (int k = 0; k < D_; ++k) v += nh[k]*Wv[k];
    out[256 + a] = v;                  // values
  }
}

// ---------------------------------------------------------------------------
extern "C" void kernel_launch(void* const* d_in, const int* in_sizes, int n_in,
                              void* d_out, int out_size, void* d_ws, size_t ws_size,
                              hipStream_t stream){
  const float* nf   = (const float*)d_in[0];
  const int*   ei   = (const int*)  d_in[1];
  const float* hs   = (const float*)d_in[2];
  const int*   am   = (const int*)  d_in[3];
  const float* Wl1  = (const float*)d_in[4];
  const float* Wr1  = (const float*)d_in[5];
  const float* att1 = (const float*)d_in[6];
  const float* b1   = (const float*)d_in[7];
  const float* lnw  = (const float*)d_in[8];
  const float* lnb  = (const float*)d_in[9];
  const float* Wl2  = (const float*)d_in[10];
  const float* Wr2  = (const float*)d_in[11];
  const float* att2 = (const float*)d_in[12];
  const float* b2   = (const float*)d_in[13];
  const float* Wih  = (const float*)d_in[14];
  const float* Whh  = (const float*)d_in[15];
  const float* bih  = (const float*)d_in[16];
  const float* bhh  = (const float*)d_in[17];
  const float* Wa   = (const float*)d_in[18];
  const float* ba   = (const float*)d_in[19];
  const float* Wv   = (const float*)d_in[20];
  const float* bv   = (const float*)d_in[21];
  float* out = (float*)d_out;

  char* ws = (char*)d_ws;
  float* h_c        = (float*)(ws);                 // 16*65*128 f32 = 520 KiB
  float* xl2_c      = (float*)(ws + 532480);        // 520 KiB
  float* xr2        = (float*)(ws + 1064960);       // 8 KiB
  float* af         = (float*)(ws + 1073152);       // 8 KiB
  int*   agent_node = (int*)  (ws + 1081344);       // 64 B
  int*   ncount     = (int*)  (ws + 1081408);       // 4 KiB
  int*   nbrs       = (int*)  (ws + 1085504);       // 1000*64*4 = 250 KiB

  k_init <<<(A_*N_ + 255)/256, 256, 0, stream>>>(nf, agent_node, ncount);
  k_scan <<<(E_ + 255)/256, 256, 0, stream>>>(ei, ncount, nbrs);
  k_attn1<<<(A_*SLOTS_ + 3)/4, 256, 0, stream>>>(nf, agent_node, ncount, nbrs,
                                                 Wl1, Wr1, att1, b1, lnw, lnb, h_c);
  k_gemm2<<<(A_*(SLOTS_+1) + 3)/4, 256, 0, stream>>>(h_c, agent_node, ncount,
                                                     Wl2, Wr2, xl2_c, xr2);
  k_attn2<<<(A_ + 3)/4, 256, 0, stream>>>(xl2_c, xr2, agent_node, ncount, att2, b2, af);
  k_gru  <<<A_, D_, 0, stream>>>(af, hs, Wih, Whh, bih, bhh, Wa, ba, Wv, bv, am, out);
}